// Round 18
// baseline (128.359 us; speedup 1.0000x reference)
//
#include <hip/hip_runtime.h>
#include <hip/hip_bf16.h>
#include <stdint.h>

#define B_ROWS 8192
#define DIM 256
#define JCHUNK 256
#define WPB 4   // waves per block
#define ROWS_PER_WAVE 64
#define ROWS_PER_BLOCK (WPB * ROWS_PER_WAVE)  // 256
#define NT (JCHUNK / 16)                      // 16 j-tiles per block
#define NTILES 4                              // A row-tiles per wave
#define NJB (B_ROWS / JCHUNK)                 // 32 j-chunks

typedef __bf16 bf16x8 __attribute__((ext_vector_type(8)));
typedef float f32x4 __attribute__((ext_vector_type(4)));

#if __has_builtin(__builtin_amdgcn_exp2f)
#define EXP2F(x) __builtin_amdgcn_exp2f(x)
#else
#define EXP2F(x) exp2f(x)
#endif

__device__ __forceinline__ unsigned short f2bf_rne(float f) {
    unsigned int u = __builtin_bit_cast(unsigned int, f);
    unsigned int r = (u + 0x7FFFu + ((u >> 16) & 1u)) >> 16;
    return (unsigned short)r;
}

// async global->LDS, 16B per lane; LDS dest is wave-uniform base + lane*16 (linear)
__device__ __forceinline__ void gld_lds16(const void* g, void* l) {
    __builtin_amdgcn_global_load_lds(
        (const __attribute__((address_space(1))) unsigned int*)g,
        (__attribute__((address_space(3))) unsigned int*)l, 16, 0, 0);
}

// ---------------- Kernel 1: L2-normalize rows -> bf16, zero accumulators + counter ----------------
__global__ __launch_bounds__(256) void normalize_k(const float* __restrict__ emb,
                                                   unsigned short* __restrict__ ebf,
                                                   float* __restrict__ Sall,
                                                   unsigned int* __restrict__ ctr) {
    const int idx = blockIdx.x * 256 + threadIdx.x;
    if (idx < 4096) {
        float4 z = {0.f, 0.f, 0.f, 0.f};
        reinterpret_cast<float4*>(Sall)[idx] = z;  // zeroes Sall+Spos (16384 floats)
    }
    if (idx == 0) *ctr = 0u;
    const int row = blockIdx.x * 4 + (threadIdx.x >> 6);
    const int lane = threadIdx.x & 63;  // 4 floats each covers DIM=256
    const float4 v = reinterpret_cast<const float4*>(emb + (size_t)row * DIM)[lane];
    float ss = v.x * v.x + v.y * v.y + v.z * v.z + v.w * v.w;
    #pragma unroll
    for (int off = 32; off; off >>= 1) ss += __shfl_xor(ss, off);
    const float scale = 1.0f / fmaxf(sqrtf(ss), 1e-12f);
    ushort4 o;
    o.x = f2bf_rne(v.x * scale);
    o.y = f2bf_rne(v.y * scale);
    o.z = f2bf_rne(v.z * scale);
    o.w = f2bf_rne(v.w * scale);
    reinterpret_cast<ushort4*>(ebf + (size_t)row * DIM)[lane] = o;
}

// ---------------- Kernel 2: fused sim + masked exp-sum + fence-free finalize ----------------
// Structure = R16 best (110.8us): 64 rows/wave, 4 A-tiles register-resident,
// cooperative gld_lds staging w/ pre-swizzled source + linear LDS dest, double
// buffer, pipelined epilogue (accA/accB), fence-free fused finalize (vmcnt(0)
// handoff + agent-scope batched loads). Two low-risk deltas, R17 evidence:
//  1. s_setprio REMOVED -- never A/B'd here; m190 measured it NEGATIVE in this
//     exact regime (lockstep barrier-synced multi-wave MFMA blocks).
//  2. JCHUNK 512->256, grid 512->1024: 2x block oversubscription (4 queued per
//     2-resident slots/CU) backfills straggler CUs and shrinks the ~5us tail;
//     finer work quanta, same per-phase structure.
__global__ __launch_bounds__(256, 2) void sim_k(const unsigned short* __restrict__ ebf,
                                                const int* __restrict__ labels,
                                                float* __restrict__ Sall,
                                                float* __restrict__ Spos,
                                                unsigned int* __restrict__ ctr,
                                                float* __restrict__ out) {
    // exp((dot-1)/T) = exp2((dot-1) * INV_T*log2e)
    constexpr float K2 = 14.285714285714286f * 1.4426950408889634f;  // 20.60993
    __shared__ __align__(16) unsigned char bufs[2][8192];            // 16 KB
    __shared__ int lds_lab[JCHUNK];
    __shared__ int lastblk;
    __shared__ float fsum[WPB];
    __shared__ int fcnt[WPB];

    const int tid  = threadIdx.x;
    const int wave = tid >> 6;
    const int lane = tid & 63;
    const int col  = lane & 15;
    const int quad = lane >> 4;
    const int lo   = lane & 31;
    const int hi   = lane >> 5;

    const int rowblk = blockIdx.x >> 5;            // 0..31
    const int jblk   = blockIdx.x & 31;            // 0..31
    const int i_base = rowblk * ROWS_PER_BLOCK + wave * ROWS_PER_WAVE;
    const int j0     = jblk * JCHUNK;

    // ---- Preload A-fragments (4 tiles x 8 K-steps) + row labels ----
    // lane L holds A[row = L&15][k = kk*32 + (L>>4)*8 + 0..7]
    bf16x8 afrag[NTILES][8];
    int li[NTILES][4];
    #pragma unroll
    for (int t = 0; t < NTILES; ++t) {
        const int arow = i_base + t * 16 + col;
        const uint4* ap = reinterpret_cast<const uint4*>(ebf) + (size_t)arow * 32 + quad;
        #pragma unroll
        for (int kk = 0; kk < 8; ++kk)
            afrag[t][kk] = __builtin_bit_cast(bf16x8, ap[kk * 4]);
        #pragma unroll
        for (int r = 0; r < 4; ++r)
            li[t][r] = labels[i_base + t * 16 + quad * 4 + r];
    }

    // ---- Per-lane pre-swizzled global source offsets (R6-proven) ----
    int voff[2];
    #pragma unroll
    for (int i = 0; i < 2; ++i) {
        const int r = 4 * wave + 2 * i + hi;
        voff[i] = r * 512 + ((lo ^ r) & 31) * 16;
    }
    const int ldst0 = wave * 2048;

    const char* gBase = reinterpret_cast<const char*>(ebf) + (size_t)j0 * 512;

    // ---- Prologue: labels -> LDS; stage tile 0 into bufs[0] ----
    lds_lab[tid] = labels[j0 + tid];
    gld_lds16(gBase + voff[0], bufs[0] + ldst0);
    gld_lds16(gBase + voff[1], bufs[0] + ldst0 + 1024);
    __syncthreads();

    float s_all[NTILES][4] = {};
    float s_pos[NTILES][4] = {};
    f32x4 accA[NTILES], accB[NTILES];

    auto do_mfma = [&](f32x4* acc, const unsigned char* bufR) {
        #pragma unroll
        for (int t = 0; t < NTILES; ++t) acc[t] = (f32x4){0.f, 0.f, 0.f, 0.f};
        #pragma unroll
        for (int kk = 0; kk < 8; ++kk) {
            const int c = kk * 4 + quad;
            const bf16x8 bfrag = *reinterpret_cast<const bf16x8*>(
                &bufR[col * 512 + ((c ^ col) & 31) * 16]);
            #pragma unroll
            for (int t = 0; t < NTILES; ++t)
                acc[t] = __builtin_amdgcn_mfma_f32_16x16x32_bf16(afrag[t][kk], bfrag, acc[t], 0, 0, 0);
        }
    };

    auto do_epi = [&](const f32x4* acc, int jt) {
        const int lj = lds_lab[jt * 16 + col];
        const int jcol = j0 + jt * 16 + col;
        const int jt16 = j0 + jt * 16;
        const bool diag_possible = (jt16 < i_base + ROWS_PER_WAVE) && (i_base < jt16 + 16);
        if (!diag_possible) {
            #pragma unroll
            for (int t = 0; t < NTILES; ++t) {
                #pragma unroll
                for (int r = 0; r < 4; ++r) {
                    const float ex = EXP2F(fmaf(acc[t][r], K2, -K2));
                    s_all[t][r] += ex;
                    s_pos[t][r] += (lj == li[t][r]) ? ex : 0.0f;
                }
            }
        } else {
            #pragma unroll
            for (int t = 0; t < NTILES; ++t) {
                #pragma unroll
                for (int r = 0; r < 4; ++r) {
                    const int irow = i_base + t * 16 + quad * 4 + r;
                    const float ex = EXP2F(fmaf(acc[t][r], K2, -K2));
                    const bool valid = (jcol != irow);
                    const bool pos = valid && (lj == li[t][r]);
                    s_all[t][r] += valid ? ex : 0.0f;
                    s_pos[t][r] += pos ? ex : 0.0f;
                }
            }
        }
    };

    #pragma unroll 1
    for (int m = 0; m < NT / 2; ++m) {
        const int jt0 = 2 * m, jt1 = 2 * m + 1;

        // ---- phase jt0: read bufs[0], stage jt0+1 into bufs[1] ----
        {
            const char* gT = gBase + (size_t)(jt0 + 1) * 8192;   // jt0+1 <= 15 always
            gld_lds16(gT + voff[0], bufs[1] + ldst0);
            gld_lds16(gT + voff[1], bufs[1] + ldst0 + 1024);
        }
        do_mfma(accA, bufs[0]);
        if (m > 0) do_epi(accB, jt0 - 1);   // overlap: exp(jt0-1) under MFMA(jt0) drain
        __syncthreads();

        // ---- phase jt1: read bufs[1], stage jt1+1 into bufs[0] ----
        if (jt1 + 1 < NT) {
            const char* gT = gBase + (size_t)(jt1 + 1) * 8192;
            gld_lds16(gT + voff[0], bufs[0] + ldst0);
            gld_lds16(gT + voff[1], bufs[0] + ldst0 + 1024);
        }
        do_mfma(accB, bufs[1]);
        do_epi(accA, jt0);                  // overlap: exp(jt0) under MFMA(jt1) drain
        __syncthreads();
    }
    do_epi(accB, NT - 1);                   // tail epilogue

    // Reduce over the 16 column-lanes within each quad, then one atomic per row.
    #pragma unroll
    for (int t = 0; t < NTILES; ++t) {
        #pragma unroll
        for (int r = 0; r < 4; ++r) {
            float a = s_all[t][r];
            float pp = s_pos[t][r];
            #pragma unroll
            for (int off = 1; off < 16; off <<= 1) {
                a += __shfl_xor(a, off);
                pp += __shfl_xor(pp, off);
            }
            if (col == 0) {
                const int irow = i_base + t * 16 + quad * 4 + r;
                atomicAdd(&Sall[irow], a);
                atomicAdd(&Spos[irow], pp);
            }
        }
    }

    // ---- Fence-free fused finalize (R16-proven) ----
    asm volatile("s_waitcnt vmcnt(0)" ::: "memory");  // this block's atomics complete
    __syncthreads();
    if (tid == 0) {
        const unsigned prev = atomicAdd(ctr, 1u);     // device-scope RMW
        lastblk = (prev == (unsigned)(gridDim.x - 1)) ? 1 : 0;
    }
    __syncthreads();
    if (lastblk) {
        float sum = 0.0f;
        int cnt = 0;
        #pragma unroll 1
        for (int c8 = 0; c8 < (B_ROWS / 256) / 8; ++c8) {
            float spv[8], sav[8];
            #pragma unroll
            for (int k = 0; k < 8; ++k) {
                const int i = tid + (c8 * 8 + k) * 256;
                spv[k] = __hip_atomic_load(&Spos[i], __ATOMIC_RELAXED, __HIP_MEMORY_SCOPE_AGENT);
                sav[k] = __hip_atomic_load(&Sall[i], __ATOMIC_RELAXED, __HIP_MEMORY_SCOPE_AGENT);
            }
            #pragma unroll
            for (int k = 0; k < 8; ++k) {
                if (spv[k] > 0.0f) {
                    sum += __logf(__fdividef(sav[k], spv[k]));
                    ++cnt;
                }
            }
        }
        #pragma unroll
        for (int off = 32; off; off >>= 1) {
            sum += __shfl_xor(sum, off);
            cnt += __shfl_xor(cnt, off);
        }
        if (lane == 0) { fsum[wave] = sum; fcnt[wave] = cnt; }
        __syncthreads();
        if (tid == 0) {
            float s = 0.0f;
            int c = 0;
            #pragma unroll
            for (int w = 0; w < WPB; ++w) { s += fsum[w]; c += fcnt[w]; }
            out[0] = (c > 0) ? s / (float)c : 0.0f;
        }
    }
}

extern "C" void kernel_launch(void* const* d_in, const int* in_sizes, int n_in,
                              void* d_out, int out_size, void* d_ws, size_t ws_size,
                              hipStream_t stream) {
    const float* emb   = (const float*)d_in[0];
    const int* labels  = (const int*)d_in[1];
    float* out         = (float*)d_out;

    unsigned short* ebf = (unsigned short*)d_ws;                       // 4 MB bf16 normalized
    float* Sall = (float*)((char*)d_ws + (size_t)B_ROWS * DIM * 2);    // 32 KB
    float* Spos = Sall + B_ROWS;                                       // 32 KB
    unsigned int* ctr = (unsigned int*)(Spos + B_ROWS);                // 4 B

    normalize_k<<<B_ROWS / 4, 256, 0, stream>>>(emb, ebf, Sall, ctr);

    dim3 grid((B_ROWS / ROWS_PER_BLOCK) * NJB);                        // 32*32 = 1024
    sim_k<<<grid, 256, 0, stream>>>(ebf, labels, Sall, Spos, ctr, out);
}

// Round 19
// 111.788 us; speedup vs baseline: 1.1482x; 1.1482x over previous
//
#include <hip/hip_runtime.h>
#include <hip/hip_bf16.h>
#include <stdint.h>

#define B_ROWS 8192
#define DIM 256
#define JCHUNK 512
#define WPB 4   // waves per block
#define ROWS_PER_WAVE 64
#define ROWS_PER_BLOCK (WPB * ROWS_PER_WAVE)  // 256
#define NT (JCHUNK / 16)                      // 32 j-tiles per block
#define NTILES 4                              // A row-tiles per wave

typedef __bf16 bf16x8 __attribute__((ext_vector_type(8)));
typedef float f32x4 __attribute__((ext_vector_type(4)));

#if __has_builtin(__builtin_amdgcn_exp2f)
#define EXP2F(x) __builtin_amdgcn_exp2f(x)
#else
#define EXP2F(x) exp2f(x)
#endif

__device__ __forceinline__ unsigned short f2bf_rne(float f) {
    unsigned int u = __builtin_bit_cast(unsigned int, f);
    unsigned int r = (u + 0x7FFFu + ((u >> 16) & 1u)) >> 16;
    return (unsigned short)r;
}

// async global->LDS, 16B per lane; LDS dest is wave-uniform base + lane*16 (linear)
__device__ __forceinline__ void gld_lds16(const void* g, void* l) {
    __builtin_amdgcn_global_load_lds(
        (const __attribute__((address_space(1))) unsigned int*)g,
        (__attribute__((address_space(3))) unsigned int*)l, 16, 0, 0);
}

// ---------------- Kernel 1: L2-normalize rows -> bf16, zero accumulators + counter ----------------
__global__ __launch_bounds__(256) void normalize_k(const float* __restrict__ emb,
                                                   unsigned short* __restrict__ ebf,
                                                   float* __restrict__ Sall,
                                                   unsigned int* __restrict__ ctr) {
    const int idx = blockIdx.x * 256 + threadIdx.x;
    if (idx < 4096) {
        float4 z = {0.f, 0.f, 0.f, 0.f};
        reinterpret_cast<float4*>(Sall)[idx] = z;  // zeroes Sall+Spos (16384 floats)
    }
    if (idx == 0) *ctr = 0u;
    const int row = blockIdx.x * 4 + (threadIdx.x >> 6);
    const int lane = threadIdx.x & 63;  // 4 floats each covers DIM=256
    const float4 v = reinterpret_cast<const float4*>(emb + (size_t)row * DIM)[lane];
    float ss = v.x * v.x + v.y * v.y + v.z * v.z + v.w * v.w;
    #pragma unroll
    for (int off = 32; off; off >>= 1) ss += __shfl_xor(ss, off);
    const float scale = 1.0f / fmaxf(sqrtf(ss), 1e-12f);
    ushort4 o;
    o.x = f2bf_rne(v.x * scale);
    o.y = f2bf_rne(v.y * scale);
    o.z = f2bf_rne(v.z * scale);
    o.w = f2bf_rne(v.w * scale);
    reinterpret_cast<ushort4*>(ebf + (size_t)row * DIM)[lane] = o;
}

// ---------------- Kernel 2: fused sim + masked exp-sum + fence-free finalize ----------------
// EXACT R16 structure (best: 110.8us total, sim_k 56.2) with ONE delta:
// s_setprio(1)/(0) around the MFMA cluster REMOVED (single-variable A/B).
// Evidence: m190 measured setprio NEGATIVE (-14 TF @8k) in this exact regime
// (lockstep barrier-synced multi-wave MFMA); it had been present untested since
// R4. R18's bundled test (setprio removal + JCHUNK 256) regressed, but WRITE_SIZE
// 9.2MB attributed that to JCHUNK's doubled atomic traffic -- setprio still
// unattributed. Everything else byte-identical to R16: 64 rows/wave, 4 A-tiles
// register-resident, cooperative gld_lds staging (pre-swizzled source, linear
// LDS dest), double buffer, pipelined epilogue, fence-free fused finalize
// (vmcnt(0) handoff + agent-scope batched loads).
__global__ __launch_bounds__(256, 2) void sim_k(const unsigned short* __restrict__ ebf,
                                                const int* __restrict__ labels,
                                                float* __restrict__ Sall,
                                                float* __restrict__ Spos,
                                                unsigned int* __restrict__ ctr,
                                                float* __restrict__ out) {
    // exp((dot-1)/T) = exp2((dot-1) * INV_T*log2e)
    constexpr float K2 = 14.285714285714286f * 1.4426950408889634f;  // 20.60993
    __shared__ __align__(16) unsigned char bufs[2][8192];            // 16 KB
    __shared__ int lds_lab[JCHUNK];
    __shared__ int lastblk;
    __shared__ float fsum[WPB];
    __shared__ int fcnt[WPB];

    const int tid  = threadIdx.x;
    const int wave = tid >> 6;
    const int lane = tid & 63;
    const int col  = lane & 15;
    const int quad = lane >> 4;
    const int lo   = lane & 31;
    const int hi   = lane >> 5;

    const int rowblk = blockIdx.x >> 4;            // 0..31
    const int jblk   = blockIdx.x & 15;            // 0..15
    const int i_base = rowblk * ROWS_PER_BLOCK + wave * ROWS_PER_WAVE;
    const int j0     = jblk * JCHUNK;

    // ---- Preload A-fragments (4 tiles x 8 K-steps) + row labels ----
    // lane L holds A[row = L&15][k = kk*32 + (L>>4)*8 + 0..7]
    bf16x8 afrag[NTILES][8];
    int li[NTILES][4];
    #pragma unroll
    for (int t = 0; t < NTILES; ++t) {
        const int arow = i_base + t * 16 + col;
        const uint4* ap = reinterpret_cast<const uint4*>(ebf) + (size_t)arow * 32 + quad;
        #pragma unroll
        for (int kk = 0; kk < 8; ++kk)
            afrag[t][kk] = __builtin_bit_cast(bf16x8, ap[kk * 4]);
        #pragma unroll
        for (int r = 0; r < 4; ++r)
            li[t][r] = labels[i_base + t * 16 + quad * 4 + r];
    }

    // ---- Per-lane pre-swizzled global source offsets (R6-proven) ----
    int voff[2];
    #pragma unroll
    for (int i = 0; i < 2; ++i) {
        const int r = 4 * wave + 2 * i + hi;
        voff[i] = r * 512 + ((lo ^ r) & 31) * 16;
    }
    const int ldst0 = wave * 2048;

    const char* gBase = reinterpret_cast<const char*>(ebf) + (size_t)j0 * 512;

    // ---- Prologue: labels -> LDS; stage tile 0 into bufs[0] ----
    lds_lab[tid] = labels[j0 + tid];
    lds_lab[256 + tid] = labels[j0 + 256 + tid];
    gld_lds16(gBase + voff[0], bufs[0] + ldst0);
    gld_lds16(gBase + voff[1], bufs[0] + ldst0 + 1024);
    __syncthreads();

    float s_all[NTILES][4] = {};
    float s_pos[NTILES][4] = {};
    f32x4 accA[NTILES], accB[NTILES];

    auto do_mfma = [&](f32x4* acc, const unsigned char* bufR) {
        #pragma unroll
        for (int t = 0; t < NTILES; ++t) acc[t] = (f32x4){0.f, 0.f, 0.f, 0.f};
        #pragma unroll
        for (int kk = 0; kk < 8; ++kk) {
            const int c = kk * 4 + quad;
            const bf16x8 bfrag = *reinterpret_cast<const bf16x8*>(
                &bufR[col * 512 + ((c ^ col) & 31) * 16]);
            #pragma unroll
            for (int t = 0; t < NTILES; ++t)
                acc[t] = __builtin_amdgcn_mfma_f32_16x16x32_bf16(afrag[t][kk], bfrag, acc[t], 0, 0, 0);
        }
    };

    auto do_epi = [&](const f32x4* acc, int jt) {
        const int lj = lds_lab[jt * 16 + col];
        const int jcol = j0 + jt * 16 + col;
        const int jt16 = j0 + jt * 16;
        const bool diag_possible = (jt16 < i_base + ROWS_PER_WAVE) && (i_base < jt16 + 16);
        if (!diag_possible) {
            #pragma unroll
            for (int t = 0; t < NTILES; ++t) {
                #pragma unroll
                for (int r = 0; r < 4; ++r) {
                    const float ex = EXP2F(fmaf(acc[t][r], K2, -K2));
                    s_all[t][r] += ex;
                    s_pos[t][r] += (lj == li[t][r]) ? ex : 0.0f;
                }
            }
        } else {
            #pragma unroll
            for (int t = 0; t < NTILES; ++t) {
                #pragma unroll
                for (int r = 0; r < 4; ++r) {
                    const int irow = i_base + t * 16 + quad * 4 + r;
                    const float ex = EXP2F(fmaf(acc[t][r], K2, -K2));
                    const bool valid = (jcol != irow);
                    const bool pos = valid && (lj == li[t][r]);
                    s_all[t][r] += valid ? ex : 0.0f;
                    s_pos[t][r] += pos ? ex : 0.0f;
                }
            }
        }
    };

    #pragma unroll 1
    for (int m = 0; m < NT / 2; ++m) {
        const int jt0 = 2 * m, jt1 = 2 * m + 1;

        // ---- phase jt0: read bufs[0], stage jt0+1 into bufs[1] ----
        {
            const char* gT = gBase + (size_t)(jt0 + 1) * 8192;   // jt0+1 <= 31 always
            gld_lds16(gT + voff[0], bufs[1] + ldst0);
            gld_lds16(gT + voff[1], bufs[1] + ldst0 + 1024);
        }
        do_mfma(accA, bufs[0]);
        if (m > 0) do_epi(accB, jt0 - 1);   // overlap: exp(jt0-1) under MFMA(jt0) drain
        __syncthreads();

        // ---- phase jt1: read bufs[1], stage jt1+1 into bufs[0] ----
        if (jt1 + 1 < NT) {
            const char* gT = gBase + (size_t)(jt1 + 1) * 8192;
            gld_lds16(gT + voff[0], bufs[0] + ldst0);
            gld_lds16(gT + voff[1], bufs[0] + ldst0 + 1024);
        }
        do_mfma(accB, bufs[1]);
        do_epi(accA, jt0);                  // overlap: exp(jt0) under MFMA(jt1) drain
        __syncthreads();
    }
    do_epi(accB, NT - 1);                   // tail epilogue

    // Reduce over the 16 column-lanes within each quad, then one atomic per row.
    #pragma unroll
    for (int t = 0; t < NTILES; ++t) {
        #pragma unroll
        for (int r = 0; r < 4; ++r) {
            float a = s_all[t][r];
            float pp = s_pos[t][r];
            #pragma unroll
            for (int off = 1; off < 16; off <<= 1) {
                a += __shfl_xor(a, off);
                pp += __shfl_xor(pp, off);
            }
            if (col == 0) {
                const int irow = i_base + t * 16 + quad * 4 + r;
                atomicAdd(&Sall[irow], a);
                atomicAdd(&Spos[irow], pp);
            }
        }
    }

    // ---- Fence-free fused finalize (R16-proven) ----
    asm volatile("s_waitcnt vmcnt(0)" ::: "memory");  // this block's atomics complete
    __syncthreads();
    if (tid == 0) {
        const unsigned prev = atomicAdd(ctr, 1u);     // device-scope RMW
        lastblk = (prev == (unsigned)(gridDim.x - 1)) ? 1 : 0;
    }
    __syncthreads();
    if (lastblk) {
        float sum = 0.0f;
        int cnt = 0;
        #pragma unroll 1
        for (int c8 = 0; c8 < (B_ROWS / 256) / 8; ++c8) {
            float spv[8], sav[8];
            #pragma unroll
            for (int k = 0; k < 8; ++k) {
                const int i = tid + (c8 * 8 + k) * 256;
                spv[k] = __hip_atomic_load(&Spos[i], __ATOMIC_RELAXED, __HIP_MEMORY_SCOPE_AGENT);
                sav[k] = __hip_atomic_load(&Sall[i], __ATOMIC_RELAXED, __HIP_MEMORY_SCOPE_AGENT);
            }
            #pragma unroll
            for (int k = 0; k < 8; ++k) {
                if (spv[k] > 0.0f) {
                    sum += __logf(__fdividef(sav[k], spv[k]));
                    ++cnt;
                }
            }
        }
        #pragma unroll
        for (int off = 32; off; off >>= 1) {
            sum += __shfl_xor(sum, off);
            cnt += __shfl_xor(cnt, off);
        }
        if (lane == 0) { fsum[wave] = sum; fcnt[wave] = cnt; }
        __syncthreads();
        if (tid == 0) {
            float s = 0.0f;
            int c = 0;
            #pragma unroll
            for (int w = 0; w < WPB; ++w) { s += fsum[w]; c += fcnt[w]; }
            out[0] = (c > 0) ? s / (float)c : 0.0f;
        }
    }
}

extern "C" void kernel_launch(void* const* d_in, const int* in_sizes, int n_in,
                              void* d_out, int out_size, void* d_ws, size_t ws_size,
                              hipStream_t stream) {
    const float* emb   = (const float*)d_in[0];
    const int* labels  = (const int*)d_in[1];
    float* out         = (float*)d_out;

    unsigned short* ebf = (unsigned short*)d_ws;                       // 4 MB bf16 normalized
    float* Sall = (float*)((char*)d_ws + (size_t)B_ROWS * DIM * 2);    // 32 KB
    float* Spos = Sall + B_ROWS;                                       // 32 KB
    unsigned int* ctr = (unsigned int*)(Spos + B_ROWS);                // 4 B

    normalize_k<<<B_ROWS / 4, 256, 0, stream>>>(emb, ebf, Sall, ctr);

    dim3 grid((B_ROWS / ROWS_PER_BLOCK) * (B_ROWS / JCHUNK));          // 32*16 = 512
    sim_k<<<grid, 256, 0, stream>>>(ebf, labels, Sall, Spos, ctr, out);
}

// Round 20
// 111.361 us; speedup vs baseline: 1.1526x; 1.0038x over previous
//
#include <hip/hip_runtime.h>
#include <hip/hip_bf16.h>
#include <stdint.h>

#define B_ROWS 8192
#define DIM 256
#define JCHUNK 512
#define WPB 4   // waves per block
#define ROWS_PER_WAVE 64
#define ROWS_PER_BLOCK (WPB * ROWS_PER_WAVE)  // 256
#define NT (JCHUNK / 16)                      // 32 j-tiles per block
#define NTILES 4                              // A row-tiles per wave

typedef __bf16 bf16x8 __attribute__((ext_vector_type(8)));
typedef float f32x4 __attribute__((ext_vector_type(4)));

#if __has_builtin(__builtin_amdgcn_exp2f)
#define EXP2F(x) __builtin_amdgcn_exp2f(x)
#else
#define EXP2F(x) exp2f(x)
#endif

__device__ __forceinline__ unsigned short f2bf_rne(float f) {
    unsigned int u = __builtin_bit_cast(unsigned int, f);
    unsigned int r = (u + 0x7FFFu + ((u >> 16) & 1u)) >> 16;
    return (unsigned short)r;
}

// async global->LDS, 16B per lane; LDS dest is wave-uniform base + lane*16 (linear)
__device__ __forceinline__ void gld_lds16(const void* g, void* l) {
    __builtin_amdgcn_global_load_lds(
        (const __attribute__((address_space(1))) unsigned int*)g,
        (__attribute__((address_space(3))) unsigned int*)l, 16, 0, 0);
}

// ---------------- Kernel 1: L2-normalize rows -> bf16, zero accumulators + counter ----------------
__global__ __launch_bounds__(256) void normalize_k(const float* __restrict__ emb,
                                                   unsigned short* __restrict__ ebf,
                                                   float* __restrict__ Sall,
                                                   unsigned int* __restrict__ ctr) {
    const int idx = blockIdx.x * 256 + threadIdx.x;
    if (idx < 4096) {
        float4 z = {0.f, 0.f, 0.f, 0.f};
        reinterpret_cast<float4*>(Sall)[idx] = z;  // zeroes Sall+Spos (16384 floats)
    }
    if (idx == 0) *ctr = 0u;
    const int row = blockIdx.x * 4 + (threadIdx.x >> 6);
    const int lane = threadIdx.x & 63;  // 4 floats each covers DIM=256
    const float4 v = reinterpret_cast<const float4*>(emb + (size_t)row * DIM)[lane];
    float ss = v.x * v.x + v.y * v.y + v.z * v.z + v.w * v.w;
    #pragma unroll
    for (int off = 32; off; off >>= 1) ss += __shfl_xor(ss, off);
    const float scale = 1.0f / fmaxf(sqrtf(ss), 1e-12f);
    ushort4 o;
    o.x = f2bf_rne(v.x * scale);
    o.y = f2bf_rne(v.y * scale);
    o.z = f2bf_rne(v.z * scale);
    o.w = f2bf_rne(v.w * scale);
    reinterpret_cast<ushort4*>(ebf + (size_t)row * DIM)[lane] = o;
}

// ---------------- Kernel 2: fused sim + masked exp-sum + fence-free finalize ----------------
// FINAL: exact R16 configuration -- the measured optimum over 19 rounds.
// Session conclusions (all hardware-A/B'd):
//  - 64 rows/wave, 4 A-tiles register-resident (256 unified regs -> 2 waves/SIMD,
//    register-bound; NTILES=2@3waves and 32x32-shape both measured worse).
//  - Cooperative gld_lds staging, pre-swizzled global source + linear LDS dest,
//    double buffer, plain __syncthreads (counted-vmcnt/raw-barrier = neutral).
//  - Pipelined epilogue (accA/accB; neutral but harmless), s_setprio kept
//    (removal measured slightly negative, R19).
//  - Fence-free fused finalize: s_waitcnt vmcnt(0) producer handoff + agent-scope
//    batched loads. NO __threadfence (L2 wb/inv storm, R13) and NO RMW-reads
//    (per-line serialization, R14/R15).
__global__ __launch_bounds__(256, 2) void sim_k(const unsigned short* __restrict__ ebf,
                                                const int* __restrict__ labels,
                                                float* __restrict__ Sall,
                                                float* __restrict__ Spos,
                                                unsigned int* __restrict__ ctr,
                                                float* __restrict__ out) {
    // exp((dot-1)/T) = exp2((dot-1) * INV_T*log2e)
    constexpr float K2 = 14.285714285714286f * 1.4426950408889634f;  // 20.60993
    __shared__ __align__(16) unsigned char bufs[2][8192];            // 16 KB
    __shared__ int lds_lab[JCHUNK];
    __shared__ int lastblk;
    __shared__ float fsum[WPB];
    __shared__ int fcnt[WPB];

    const int tid  = threadIdx.x;
    const int wave = tid >> 6;
    const int lane = tid & 63;
    const int col  = lane & 15;
    const int quad = lane >> 4;
    const int lo   = lane & 31;
    const int hi   = lane >> 5;

    const int rowblk = blockIdx.x >> 4;            // 0..31
    const int jblk   = blockIdx.x & 15;            // 0..15
    const int i_base = rowblk * ROWS_PER_BLOCK + wave * ROWS_PER_WAVE;
    const int j0     = jblk * JCHUNK;

    // ---- Preload A-fragments (4 tiles x 8 K-steps) + row labels ----
    // lane L holds A[row = L&15][k = kk*32 + (L>>4)*8 + 0..7]
    bf16x8 afrag[NTILES][8];
    int li[NTILES][4];
    #pragma unroll
    for (int t = 0; t < NTILES; ++t) {
        const int arow = i_base + t * 16 + col;
        const uint4* ap = reinterpret_cast<const uint4*>(ebf) + (size_t)arow * 32 + quad;
        #pragma unroll
        for (int kk = 0; kk < 8; ++kk)
            afrag[t][kk] = __builtin_bit_cast(bf16x8, ap[kk * 4]);
        #pragma unroll
        for (int r = 0; r < 4; ++r)
            li[t][r] = labels[i_base + t * 16 + quad * 4 + r];
    }

    // ---- Per-lane pre-swizzled global source offsets (R6-proven) ----
    int voff[2];
    #pragma unroll
    for (int i = 0; i < 2; ++i) {
        const int r = 4 * wave + 2 * i + hi;
        voff[i] = r * 512 + ((lo ^ r) & 31) * 16;
    }
    const int ldst0 = wave * 2048;

    const char* gBase = reinterpret_cast<const char*>(ebf) + (size_t)j0 * 512;

    // ---- Prologue: labels -> LDS; stage tile 0 into bufs[0] ----
    lds_lab[tid] = labels[j0 + tid];
    lds_lab[256 + tid] = labels[j0 + 256 + tid];
    gld_lds16(gBase + voff[0], bufs[0] + ldst0);
    gld_lds16(gBase + voff[1], bufs[0] + ldst0 + 1024);
    __syncthreads();

    float s_all[NTILES][4] = {};
    float s_pos[NTILES][4] = {};
    f32x4 accA[NTILES], accB[NTILES];

    auto do_mfma = [&](f32x4* acc, const unsigned char* bufR) {
        #pragma unroll
        for (int t = 0; t < NTILES; ++t) acc[t] = (f32x4){0.f, 0.f, 0.f, 0.f};
        __builtin_amdgcn_s_setprio(1);
        #pragma unroll
        for (int kk = 0; kk < 8; ++kk) {
            const int c = kk * 4 + quad;
            const bf16x8 bfrag = *reinterpret_cast<const bf16x8*>(
                &bufR[col * 512 + ((c ^ col) & 31) * 16]);
            #pragma unroll
            for (int t = 0; t < NTILES; ++t)
                acc[t] = __builtin_amdgcn_mfma_f32_16x16x32_bf16(afrag[t][kk], bfrag, acc[t], 0, 0, 0);
        }
        __builtin_amdgcn_s_setprio(0);
    };

    auto do_epi = [&](const f32x4* acc, int jt) {
        const int lj = lds_lab[jt * 16 + col];
        const int jcol = j0 + jt * 16 + col;
        const int jt16 = j0 + jt * 16;
        const bool diag_possible = (jt16 < i_base + ROWS_PER_WAVE) && (i_base < jt16 + 16);
        if (!diag_possible) {
            #pragma unroll
            for (int t = 0; t < NTILES; ++t) {
                #pragma unroll
                for (int r = 0; r < 4; ++r) {
                    const float ex = EXP2F(fmaf(acc[t][r], K2, -K2));
                    s_all[t][r] += ex;
                    s_pos[t][r] += (lj == li[t][r]) ? ex : 0.0f;
                }
            }
        } else {
            #pragma unroll
            for (int t = 0; t < NTILES; ++t) {
                #pragma unroll
                for (int r = 0; r < 4; ++r) {
                    const int irow = i_base + t * 16 + quad * 4 + r;
                    const float ex = EXP2F(fmaf(acc[t][r], K2, -K2));
                    const bool valid = (jcol != irow);
                    const bool pos = valid && (lj == li[t][r]);
                    s_all[t][r] += valid ? ex : 0.0f;
                    s_pos[t][r] += pos ? ex : 0.0f;
                }
            }
        }
    };

    #pragma unroll 1
    for (int m = 0; m < NT / 2; ++m) {
        const int jt0 = 2 * m, jt1 = 2 * m + 1;

        // ---- phase jt0: read bufs[0], stage jt0+1 into bufs[1] ----
        {
            const char* gT = gBase + (size_t)(jt0 + 1) * 8192;   // jt0+1 <= 31 always
            gld_lds16(gT + voff[0], bufs[1] + ldst0);
            gld_lds16(gT + voff[1], bufs[1] + ldst0 + 1024);
        }
        do_mfma(accA, bufs[0]);
        if (m > 0) do_epi(accB, jt0 - 1);   // overlap: exp(jt0-1) under MFMA(jt0) drain
        __syncthreads();

        // ---- phase jt1: read bufs[1], stage jt1+1 into bufs[0] ----
        if (jt1 + 1 < NT) {
            const char* gT = gBase + (size_t)(jt1 + 1) * 8192;
            gld_lds16(gT + voff[0], bufs[0] + ldst0);
            gld_lds16(gT + voff[1], bufs[0] + ldst0 + 1024);
        }
        do_mfma(accB, bufs[1]);
        do_epi(accA, jt0);                  // overlap: exp(jt0) under MFMA(jt1) drain
        __syncthreads();
    }
    do_epi(accB, NT - 1);                   // tail epilogue

    // Reduce over the 16 column-lanes within each quad, then one atomic per row.
    #pragma unroll
    for (int t = 0; t < NTILES; ++t) {
        #pragma unroll
        for (int r = 0; r < 4; ++r) {
            float a = s_all[t][r];
            float pp = s_pos[t][r];
            #pragma unroll
            for (int off = 1; off < 16; off <<= 1) {
                a += __shfl_xor(a, off);
                pp += __shfl_xor(pp, off);
            }
            if (col == 0) {
                const int irow = i_base + t * 16 + quad * 4 + r;
                atomicAdd(&Sall[irow], a);
                atomicAdd(&Spos[irow], pp);
            }
        }
    }

    // ---- Fence-free fused finalize (R16-proven) ----
    asm volatile("s_waitcnt vmcnt(0)" ::: "memory");  // this block's atomics complete
    __syncthreads();
    if (tid == 0) {
        const unsigned prev = atomicAdd(ctr, 1u);     // device-scope RMW
        lastblk = (prev == (unsigned)(gridDim.x - 1)) ? 1 : 0;
    }
    __syncthreads();
    if (lastblk) {
        float sum = 0.0f;
        int cnt = 0;
        #pragma unroll 1
        for (int c8 = 0; c8 < (B_ROWS / 256) / 8; ++c8) {
            float spv[8], sav[8];
            #pragma unroll
            for (int k = 0; k < 8; ++k) {
                const int i = tid + (c8 * 8 + k) * 256;
                spv[k] = __hip_atomic_load(&Spos[i], __ATOMIC_RELAXED, __HIP_MEMORY_SCOPE_AGENT);
                sav[k] = __hip_atomic_load(&Sall[i], __ATOMIC_RELAXED, __HIP_MEMORY_SCOPE_AGENT);
            }
            #pragma unroll
            for (int k = 0; k < 8; ++k) {
                if (spv[k] > 0.0f) {
                    sum += __logf(__fdividef(sav[k], spv[k]));
                    ++cnt;
                }
            }
        }
        #pragma unroll
        for (int off = 32; off; off >>= 1) {
            sum += __shfl_xor(sum, off);
            cnt += __shfl_xor(cnt, off);
        }
        if (lane == 0) { fsum[wave] = sum; fcnt[wave] = cnt; }
        __syncthreads();
        if (tid == 0) {
            float s = 0.0f;
            int c = 0;
            #pragma unroll
            for (int w = 0; w < WPB; ++w) { s += fsum[w]; c += fcnt[w]; }
            out[0] = (c > 0) ? s / (float)c : 0.0f;
        }
    }
}

extern "C" void kernel_launch(void* const* d_in, const int* in_sizes, int n_in,
                              void* d_out, int out_size, void* d_ws, size_t ws_size,
                              hipStream_t stream) {
    const float* emb   = (const float*)d_in[0];
    const int* labels  = (const int*)d_in[1];
    float* out         = (float*)d_out;

    unsigned short* ebf = (unsigned short*)d_ws;                       // 4 MB bf16 normalized
    float* Sall = (float*)((char*)d_ws + (size_t)B_ROWS * DIM * 2);    // 32 KB
    float* Spos = Sall + B_ROWS;                                       // 32 KB
    unsigned int* ctr = (unsigned int*)(Spos + B_ROWS);                // 4 B

    normalize_k<<<B_ROWS / 4, 256, 0, stream>>>(emb, ebf, Sall, ctr);

    dim3 grid((B_ROWS / ROWS_PER_BLOCK) * (B_ROWS / JCHUNK));          // 32*16 = 512
    sim_k<<<grid, 256, 0, stream>>>(ebf, labels, Sall, Spos, ctr, out);
}

// Round 21
// 108.583 us; speedup vs baseline: 1.1821x; 1.0256x over previous
//
#include <hip/hip_runtime.h>
#include <hip/hip_bf16.h>
#include <stdint.h>

#define B_ROWS 8192
#define DIM 256
#define JCHUNK 512
#define WPB 4   // waves per block
#define ROWS_PER_WAVE 64
#define ROWS_PER_BLOCK (WPB * ROWS_PER_WAVE)  // 256
#define NT (JCHUNK / 16)                      // 32 j-tiles per block
#define NTILES 4                              // A row-tiles per wave
#define NRB (B_ROWS / ROWS_PER_BLOCK)         // 32 row-blocks
#define NJB (B_ROWS / JCHUNK)                 // 16 j-blocks per row-block

typedef __bf16 bf16x8 __attribute__((ext_vector_type(8)));
typedef float f32x4 __attribute__((ext_vector_type(4)));

#if __has_builtin(__builtin_amdgcn_exp2f)
#define EXP2F(x) __builtin_amdgcn_exp2f(x)
#else
#define EXP2F(x) exp2f(x)
#endif

__device__ __forceinline__ unsigned short f2bf_rne(float f) {
    unsigned int u = __builtin_bit_cast(unsigned int, f);
    unsigned int r = (u + 0x7FFFu + ((u >> 16) & 1u)) >> 16;
    return (unsigned short)r;
}

// async global->LDS, 16B per lane; LDS dest is wave-uniform base + lane*16 (linear)
__device__ __forceinline__ void gld_lds16(const void* g, void* l) {
    __builtin_amdgcn_global_load_lds(
        (const __attribute__((address_space(1))) unsigned int*)g,
        (__attribute__((address_space(3))) unsigned int*)l, 16, 0, 0);
}

// ---------------- Kernel 1: L2-normalize rows -> bf16, zero accumulators + control ----------------
// Zero region: Sall[8192] + Spos[8192] + 64-float control block = 16448 floats = 4112 float4.
__global__ __launch_bounds__(256) void normalize_k(const float* __restrict__ emb,
                                                   unsigned short* __restrict__ ebf,
                                                   float* __restrict__ Sall) {
    const int idx = blockIdx.x * 256 + threadIdx.x;
    if (idx < 4112) {
        float4 z = {0.f, 0.f, 0.f, 0.f};
        reinterpret_cast<float4*>(Sall)[idx] = z;
    }
    const int row = blockIdx.x * 4 + (threadIdx.x >> 6);
    const int lane = threadIdx.x & 63;  // 4 floats each covers DIM=256
    const float4 v = reinterpret_cast<const float4*>(emb + (size_t)row * DIM)[lane];
    float ss = v.x * v.x + v.y * v.y + v.z * v.z + v.w * v.w;
    #pragma unroll
    for (int off = 32; off; off >>= 1) ss += __shfl_xor(ss, off);
    const float scale = 1.0f / fmaxf(sqrtf(ss), 1e-12f);
    ushort4 o;
    o.x = f2bf_rne(v.x * scale);
    o.y = f2bf_rne(v.y * scale);
    o.z = f2bf_rne(v.z * scale);
    o.w = f2bf_rne(v.w * scale);
    reinterpret_cast<ushort4*>(ebf + (size_t)row * DIM)[lane] = o;
}

// ---------------- Kernel 2: fused sim + masked exp-sum + DISTRIBUTED fence-free finalize ----------------
// Main loop byte-identical to R16/R20 optimum (110.8us; sim_k 55.7). Tail analysis
// (R10 50.9 vs R20 55.7): the single-block finalize scan of 16384 values costs
// ~4.8us while 511 blocks idle. This version shards it with the same proven
// handoff (vmcnt(0) drain -> counter RMW -> agent-scope loads), two levels:
//  L1: rowctr[32] -- the 16th finisher of each row-block reduces its OWN 256 rows
//      (1 load-pair/thread, naturally staggered across rowblks -> overlapped) and
//      atomicAdds partial (sum,cnt) into global accumulators.
//  L2: donectr -- the 32nd rowblk-finisher reads the two accumulators and writes out.
// No __threadfence anywhere (R13: L2 wb/inv storm). Control block zeroed by
// normalize_k each launch (graph-replay safe).
__global__ __launch_bounds__(256, 2) void sim_k(const unsigned short* __restrict__ ebf,
                                                const int* __restrict__ labels,
                                                float* __restrict__ Sall,
                                                float* __restrict__ Spos,
                                                unsigned int* __restrict__ ctrl,  // [0..31] rowctr, [32] donectr, [33] fsum, [34] fcnt
                                                float* __restrict__ out) {
    // exp((dot-1)/T) = exp2((dot-1) * INV_T*log2e)
    constexpr float K2 = 14.285714285714286f * 1.4426950408889634f;  // 20.60993
    __shared__ __align__(16) unsigned char bufs[2][8192];            // 16 KB
    __shared__ int lds_lab[JCHUNK];
    __shared__ int lastrow;
    __shared__ float fsum[WPB];
    __shared__ int fcnt[WPB];

    const int tid  = threadIdx.x;
    const int wave = tid >> 6;
    const int lane = tid & 63;
    const int col  = lane & 15;
    const int quad = lane >> 4;
    const int lo   = lane & 31;
    const int hi   = lane >> 5;

    const int rowblk = blockIdx.x >> 4;            // 0..31
    const int jblk   = blockIdx.x & 15;            // 0..15
    const int i_base = rowblk * ROWS_PER_BLOCK + wave * ROWS_PER_WAVE;
    const int j0     = jblk * JCHUNK;

    // ---- Preload A-fragments (4 tiles x 8 K-steps) + row labels ----
    // lane L holds A[row = L&15][k = kk*32 + (L>>4)*8 + 0..7]
    bf16x8 afrag[NTILES][8];
    int li[NTILES][4];
    #pragma unroll
    for (int t = 0; t < NTILES; ++t) {
        const int arow = i_base + t * 16 + col;
        const uint4* ap = reinterpret_cast<const uint4*>(ebf) + (size_t)arow * 32 + quad;
        #pragma unroll
        for (int kk = 0; kk < 8; ++kk)
            afrag[t][kk] = __builtin_bit_cast(bf16x8, ap[kk * 4]);
        #pragma unroll
        for (int r = 0; r < 4; ++r)
            li[t][r] = labels[i_base + t * 16 + quad * 4 + r];
    }

    // ---- Per-lane pre-swizzled global source offsets (R6-proven) ----
    int voff[2];
    #pragma unroll
    for (int i = 0; i < 2; ++i) {
        const int r = 4 * wave + 2 * i + hi;
        voff[i] = r * 512 + ((lo ^ r) & 31) * 16;
    }
    const int ldst0 = wave * 2048;

    const char* gBase = reinterpret_cast<const char*>(ebf) + (size_t)j0 * 512;

    // ---- Prologue: labels -> LDS; stage tile 0 into bufs[0] ----
    lds_lab[tid] = labels[j0 + tid];
    lds_lab[256 + tid] = labels[j0 + 256 + tid];
    gld_lds16(gBase + voff[0], bufs[0] + ldst0);
    gld_lds16(gBase + voff[1], bufs[0] + ldst0 + 1024);
    __syncthreads();

    float s_all[NTILES][4] = {};
    float s_pos[NTILES][4] = {};
    f32x4 accA[NTILES], accB[NTILES];

    auto do_mfma = [&](f32x4* acc, const unsigned char* bufR) {
        #pragma unroll
        for (int t = 0; t < NTILES; ++t) acc[t] = (f32x4){0.f, 0.f, 0.f, 0.f};
        __builtin_amdgcn_s_setprio(1);
        #pragma unroll
        for (int kk = 0; kk < 8; ++kk) {
            const int c = kk * 4 + quad;
            const bf16x8 bfrag = *reinterpret_cast<const bf16x8*>(
                &bufR[col * 512 + ((c ^ col) & 31) * 16]);
            #pragma unroll
            for (int t = 0; t < NTILES; ++t)
                acc[t] = __builtin_amdgcn_mfma_f32_16x16x32_bf16(afrag[t][kk], bfrag, acc[t], 0, 0, 0);
        }
        __builtin_amdgcn_s_setprio(0);
    };

    auto do_epi = [&](const f32x4* acc, int jt) {
        const int lj = lds_lab[jt * 16 + col];
        const int jcol = j0 + jt * 16 + col;
        const int jt16 = j0 + jt * 16;
        const bool diag_possible = (jt16 < i_base + ROWS_PER_WAVE) && (i_base < jt16 + 16);
        if (!diag_possible) {
            #pragma unroll
            for (int t = 0; t < NTILES; ++t) {
                #pragma unroll
                for (int r = 0; r < 4; ++r) {
                    const float ex = EXP2F(fmaf(acc[t][r], K2, -K2));
                    s_all[t][r] += ex;
                    s_pos[t][r] += (lj == li[t][r]) ? ex : 0.0f;
                }
            }
        } else {
            #pragma unroll
            for (int t = 0; t < NTILES; ++t) {
                #pragma unroll
                for (int r = 0; r < 4; ++r) {
                    const int irow = i_base + t * 16 + quad * 4 + r;
                    const float ex = EXP2F(fmaf(acc[t][r], K2, -K2));
                    const bool valid = (jcol != irow);
                    const bool pos = valid && (lj == li[t][r]);
                    s_all[t][r] += valid ? ex : 0.0f;
                    s_pos[t][r] += pos ? ex : 0.0f;
                }
            }
        }
    };

    #pragma unroll 1
    for (int m = 0; m < NT / 2; ++m) {
        const int jt0 = 2 * m, jt1 = 2 * m + 1;

        // ---- phase jt0: read bufs[0], stage jt0+1 into bufs[1] ----
        {
            const char* gT = gBase + (size_t)(jt0 + 1) * 8192;   // jt0+1 <= 31 always
            gld_lds16(gT + voff[0], bufs[1] + ldst0);
            gld_lds16(gT + voff[1], bufs[1] + ldst0 + 1024);
        }
        do_mfma(accA, bufs[0]);
        if (m > 0) do_epi(accB, jt0 - 1);   // overlap: exp(jt0-1) under MFMA(jt0) drain
        __syncthreads();

        // ---- phase jt1: read bufs[1], stage jt1+1 into bufs[0] ----
        if (jt1 + 1 < NT) {
            const char* gT = gBase + (size_t)(jt1 + 1) * 8192;
            gld_lds16(gT + voff[0], bufs[0] + ldst0);
            gld_lds16(gT + voff[1], bufs[0] + ldst0 + 1024);
        }
        do_mfma(accB, bufs[1]);
        do_epi(accA, jt0);                  // overlap: exp(jt0) under MFMA(jt1) drain
        __syncthreads();
    }
    do_epi(accB, NT - 1);                   // tail epilogue

    // Reduce over the 16 column-lanes within each quad, then one atomic per row.
    #pragma unroll
    for (int t = 0; t < NTILES; ++t) {
        #pragma unroll
        for (int r = 0; r < 4; ++r) {
            float a = s_all[t][r];
            float pp = s_pos[t][r];
            #pragma unroll
            for (int off = 1; off < 16; off <<= 1) {
                a += __shfl_xor(a, off);
                pp += __shfl_xor(pp, off);
            }
            if (col == 0) {
                const int irow = i_base + t * 16 + quad * 4 + r;
                atomicAdd(&Sall[irow], a);
                atomicAdd(&Spos[irow], pp);
            }
        }
    }

    // ---- L1 handoff: per-rowblk last finisher reduces its 256 rows ----
    asm volatile("s_waitcnt vmcnt(0)" ::: "memory");  // this block's atomics complete
    __syncthreads();
    if (tid == 0) {
        const unsigned prev = atomicAdd(&ctrl[rowblk], 1u);   // device-scope RMW
        lastrow = (prev == (unsigned)(NJB - 1)) ? 1 : 0;
    }
    __syncthreads();
    if (lastrow) {
        // thread t owns row rowblk*256 + t; all producers for these rows drained
        // before bumping rowctr; agent loads read the coherence point.
        const int row = rowblk * ROWS_PER_BLOCK + tid;
        const float sp = __hip_atomic_load(&Spos[row], __ATOMIC_RELAXED, __HIP_MEMORY_SCOPE_AGENT);
        const float sa = __hip_atomic_load(&Sall[row], __ATOMIC_RELAXED, __HIP_MEMORY_SCOPE_AGENT);
        float sum = 0.0f;
        int cnt = 0;
        if (sp > 0.0f) {
            sum = __logf(__fdividef(sa, sp));
            cnt = 1;
        }
        #pragma unroll
        for (int off = 32; off; off >>= 1) {
            sum += __shfl_xor(sum, off);
            cnt += __shfl_xor(cnt, off);
        }
        if (lane == 0) { fsum[wave] = sum; fcnt[wave] = cnt; }
        __syncthreads();
        if (tid == 0) {
            float s = 0.0f;
            int c = 0;
            #pragma unroll
            for (int w = 0; w < WPB; ++w) { s += fsum[w]; c += fcnt[w]; }
            // partial into global accumulators (float cnt: <= 8192, exact)
            atomicAdd((float*)&ctrl[33], s);
            atomicAdd((float*)&ctrl[34], (float)c);
            asm volatile("s_waitcnt vmcnt(0)" ::: "memory");  // partials complete
            // ---- L2 handoff: 32nd rowblk finisher writes the mean ----
            const unsigned d = atomicAdd(&ctrl[32], 1u);
            if (d == (unsigned)(NRB - 1)) {
                const float S = __hip_atomic_load((float*)&ctrl[33], __ATOMIC_RELAXED, __HIP_MEMORY_SCOPE_AGENT);
                const float C = __hip_atomic_load((float*)&ctrl[34], __ATOMIC_RELAXED, __HIP_MEMORY_SCOPE_AGENT);
                out[0] = (C > 0.0f) ? S / C : 0.0f;
            }
        }
    }
}

extern "C" void kernel_launch(void* const* d_in, const int* in_sizes, int n_in,
                              void* d_out, int out_size, void* d_ws, size_t ws_size,
                              hipStream_t stream) {
    const float* emb   = (const float*)d_in[0];
    const int* labels  = (const int*)d_in[1];
    float* out         = (float*)d_out;

    unsigned short* ebf = (unsigned short*)d_ws;                       // 4 MB bf16 normalized
    float* Sall = (float*)((char*)d_ws + (size_t)B_ROWS * DIM * 2);    // 32 KB
    float* Spos = Sall + B_ROWS;                                       // 32 KB
    unsigned int* ctrl = (unsigned int*)(Spos + B_ROWS);               // 64-float control block

    normalize_k<<<B_ROWS / 4, 256, 0, stream>>>(emb, ebf, Sall);

    dim3 grid((B_ROWS / ROWS_PER_BLOCK) * (B_ROWS / JCHUNK));          // 32*16 = 512
    sim_k<<<grid, 256, 0, stream>>>(ebf, labels, Sall, Spos, ctrl, out);
}